// Round 3
// baseline (335.373 us; speedup 1.0000x reference)
//
#include <hip/hip_runtime.h>

// ---- static config (mirrors reference) ----
constexpr int H    = 1024;
constexpr int HD   = 64;
constexpr int NQ   = 16;
constexpr int NKV  = 4;
constexpr int E_   = 8;
constexpr int FFN  = 1024;
constexpr int B_   = 4;
constexpr int Q_   = 128;
constexpr int P_   = 8;
constexpr int PS   = 128;
constexpr int S_   = P_ * PS;                 // 1024
constexpr int T_   = B_ * Q_;                 // 512
constexpr int QKV_N = HD * (NQ + 2 * NKV);    // 1536
constexpr float EPS   = 1e-5f;
constexpr float ALPHA = 1.702f;
constexpr float LIMIT = 7.0f;
constexpr float SCALE = 0.125f;               // HD^-0.5

constexpr int MAXROWS = 1536;                 // 1024 assignments + per-expert pad to 64

typedef __attribute__((ext_vector_type(4))) float f32x4;
typedef __attribute__((ext_vector_type(8))) short s16x8;

__device__ __forceinline__ unsigned short f2bf(float f) {
    unsigned u = __float_as_uint(f);
    u += 0x7FFFu + ((u >> 16) & 1u);
    return (unsigned short)(u >> 16);
}

// ---------------- RMSNorm -> bf16 out (also zeroes cnt once) ----------------
__global__ __launch_bounds__(256) void rmsnorm_kernel(const float* __restrict__ in,
                                                      const float* __restrict__ w,
                                                      unsigned short* __restrict__ outb,
                                                      int* __restrict__ cnt) {
    int t   = blockIdx.x;
    int tid = threadIdx.x;
    if (t == 0 && tid < E_) cnt[tid] = 0;
    float4 v = ((const float4*)(in + (size_t)t * H))[tid];
    float ss = v.x * v.x + v.y * v.y + v.z * v.z + v.w * v.w;
#pragma unroll
    for (int off = 32; off; off >>= 1) ss += __shfl_down(ss, off);
    __shared__ float partial[4];
    __shared__ float s_inv;
    if ((tid & 63) == 0) partial[tid >> 6] = ss;
    __syncthreads();
    if (tid == 0)
        s_inv = rsqrtf((partial[0] + partial[1] + partial[2] + partial[3]) * (1.0f / H) + EPS);
    __syncthreads();
    float inv = s_inv;
    float4 wv = ((const float4*)w)[tid];
    ushort4 ob;
    ob.x = f2bf(v.x * wv.x * inv); ob.y = f2bf(v.y * wv.y * inv);
    ob.z = f2bf(v.z * wv.z * inv); ob.w = f2bf(v.w * wv.w * inv);
    ((ushort4*)(outb + (size_t)t * H))[tid] = ob;
}

// ---------------- tiled dense GEMM: A bf16 [M][1024] x W f32 [1024][N] ----------------
// BM=64 (4 waves x 16 rows), BN=32, BK=64 double-buffered LDS W-tile [kb][n][k&7].
__global__ __launch_bounds__(256) void gemm_dense_t(const unsigned short* __restrict__ Abf,
                                                    const float* __restrict__ W,
                                                    const float* __restrict__ bias,
                                                    const float* __restrict__ resid,
                                                    float* __restrict__ C,
                                                    float* __restrict__ Cdup, int N) {
    int nb = blockIdx.x, mb = blockIdx.y * 64;
    int tid = threadIdx.x;
    int w = tid >> 6, lane = tid & 63;
    int r16 = lane & 15, kq = lane >> 4;
    int skb = tid >> 5, sn = tid & 31;

    __shared__ unsigned short Wt[2][8][32][8];

    size_t sN = (size_t)N;
    const float* wsrc = W + (size_t)(skb * 8) * sN + nb * 32 + sn;
    const unsigned short* ap = Abf + (size_t)(mb + w * 16 + r16) * 1024 + kq * 8;

    f32x4 acc[2] = {};
    float wr[8];
#pragma unroll
    for (int j = 0; j < 8; j++) wr[j] = wsrc[(size_t)j * sN];
    {
        s16x8 p;
#pragma unroll
        for (int j = 0; j < 8; j++) p[j] = (short)f2bf(wr[j]);
        *(s16x8*)&Wt[0][skb][sn][0] = p;
    }
    __syncthreads();

#pragma unroll 2
    for (int t = 0; t < 16; t++) {
        s16x8 af[2];
#pragma unroll
        for (int ks = 0; ks < 2; ks++)
            af[ks] = *(const s16x8*)(ap + t * 64 + ks * 32);
        if (t < 15) {
            const float* ws = wsrc + (size_t)(t + 1) * 64 * sN;
#pragma unroll
            for (int j = 0; j < 8; j++) wr[j] = ws[(size_t)j * sN];
        }
#pragma unroll
        for (int ks = 0; ks < 2; ks++) {
            s16x8 b0 = *(const s16x8*)&Wt[t & 1][ks * 4 + kq][r16][0];
            s16x8 b1 = *(const s16x8*)&Wt[t & 1][ks * 4 + kq][16 + r16][0];
            acc[0] = __builtin_amdgcn_mfma_f32_16x16x32_bf16(af[ks], b0, acc[0], 0, 0, 0);
            acc[1] = __builtin_amdgcn_mfma_f32_16x16x32_bf16(af[ks], b1, acc[1], 0, 0, 0);
        }
        if (t < 15) {
            s16x8 p;
#pragma unroll
            for (int j = 0; j < 8; j++) p[j] = (short)f2bf(wr[j]);
            *(s16x8*)&Wt[(t & 1) ^ 1][skb][sn][0] = p;
        }
        __syncthreads();
    }

    int row0 = mb + w * 16 + kq * 4;
#pragma unroll
    for (int nf = 0; nf < 2; nf++) {
        int col = nb * 32 + nf * 16 + r16;
        float bcol = bias[col];
#pragma unroll
        for (int r = 0; r < 4; r++) {
            int row = row0 + r;
            float v = acc[nf][r] + bcol;
            if (resid) v += resid[(size_t)row * sN + col];
            C[(size_t)row * sN + col] = v;
            if (Cdup) Cdup[(size_t)row * sN + col] = v;
        }
    }
}

// ---------------- Attention: one block per (b, q, kvh); 4 heads/block; bf16 out ----------------
__global__ __launch_bounds__(256) void attn_group_kernel(const float* __restrict__ qkv,
                                                         const float* __restrict__ kv_cache,
                                                         const int* __restrict__ page_idx,
                                                         const float* __restrict__ sinks,
                                                         unsigned short* __restrict__ attn_bf) {
    int blk = blockIdx.x;
    int kvh = blk & 3;
    int q   = (blk >> 2) & 127;
    int b   = blk >> 9;
    int t   = b * Q_ + q;
    int tid = threadIdx.x;
    int s_lo = S_ - Q_ - 127 + q;

    __shared__ __align__(16) float Vs[128][64];
    __shared__ __align__(16) float qs4[4][64];
    __shared__ float pv[4][128];
    __shared__ float sD[4];

#pragma unroll
    for (int r = 0; r < 8; r++) {
        int l = r * 256 + tid;
        int key = l >> 4, c = l & 15;
        int s = s_lo + key;
        const float* vp;
        if (s < S_ - Q_) {
            int page = page_idx[b * P_ + (s >> 7)];
            vp = kv_cache + (size_t)page * 65536 + 32768 + (size_t)(s & 127) * (NKV * HD) + kvh * HD;
        } else {
            vp = qkv + (size_t)(b * Q_ + (s - (S_ - Q_))) * QKV_N + (NQ + NKV) * HD + kvh * HD;
        }
        ((float4*)Vs[key])[c] = *(const float4*)(vp + c * 4);
    }
    {
        int hh = tid >> 6, d2 = tid & 63;
        qs4[hh][d2] = qkv[(size_t)t * QKV_N + (kvh * 4 + hh) * HD + d2];
    }
    __syncthreads();

    {
        int key = tid & 127, hp = tid >> 7;
        int s = s_lo + key;
        const float* kp;
        if (s < S_ - Q_) {
            int page = page_idx[b * P_ + (s >> 7)];
            kp = kv_cache + (size_t)page * 65536 + (size_t)(s & 127) * (NKV * HD) + kvh * HD;
        } else {
            kp = qkv + (size_t)(b * Q_ + (s - (S_ - Q_))) * QKV_N + NQ * HD + kvh * HD;
        }
        const float4* kp4 = (const float4*)kp;
        const float4* q0p = (const float4*)qs4[hp * 2];
        const float4* q1p = (const float4*)qs4[hp * 2 + 1];
        float sc0 = 0.f, sc1 = 0.f;
#pragma unroll
        for (int d4 = 0; d4 < 16; d4++) {
            float4 kk = kp4[d4];
            float4 q0 = q0p[d4], q1 = q1p[d4];
            sc0 += q0.x * kk.x + q0.y * kk.y + q0.z * kk.z + q0.w * kk.w;
            sc1 += q1.x * kk.x + q1.y * kk.y + q1.z * kk.z + q1.w * kk.w;
        }
        pv[hp * 2][key]     = sc0 * SCALE;
        pv[hp * 2 + 1][key] = sc1 * SCALE;
    }
    __syncthreads();

    {
        int wv = tid >> 6, lane = tid & 63;
        float a0 = pv[wv][lane], a1 = pv[wv][lane + 64];
        float m = fmaxf(a0, a1);
#pragma unroll
        for (int off = 32; off; off >>= 1) m = fmaxf(m, __shfl_xor(m, off));
        float p0 = __expf(a0 - m), p1 = __expf(a1 - m);
        float l = p0 + p1;
#pragma unroll
        for (int off = 32; off; off >>= 1) l += __shfl_xor(l, off);
        pv[wv][lane] = p0;
        pv[wv][lane + 64] = p1;
        if (lane == 0) sD[wv] = l + __expf(sinks[kvh * 4 + wv] - m);
    }
    __syncthreads();

    {
        int hh = tid >> 6, d2 = tid & 63;
        float a0 = 0.f, a1 = 0.f, a2 = 0.f, a3 = 0.f;
#pragma unroll 4
        for (int i = 0; i < 128; i += 4) {
            a0 += pv[hh][i]     * Vs[i][d2];
            a1 += pv[hh][i + 1] * Vs[i + 1][d2];
            a2 += pv[hh][i + 2] * Vs[i + 2][d2];
            a3 += pv[hh][i + 3] * Vs[i + 3][d2];
        }
        float acc = ((a0 + a1) + (a2 + a3)) / sD[hh];
        attn_bf[(size_t)t * (NQ * HD) + (kvh * 4 + hh) * HD + d2] = f2bf(acc);
    }
}

// ---------------- fused RMSNorm2 + router ----------------
__global__ __launch_bounds__(256) void rms_router_kernel(const float* __restrict__ hbuf,
                                                         const float* __restrict__ ln2w,
                                                         const float* __restrict__ w_router,
                                                         const float* __restrict__ b_router,
                                                         unsigned short* __restrict__ x2bf,
                                                         int* __restrict__ ridx,
                                                         float* __restrict__ rwt,
                                                         int* __restrict__ cnt) {
    int t = blockIdx.x;
    int tid = threadIdx.x;
    float4 v = ((const float4*)(hbuf + (size_t)t * H))[tid];
    float ss = v.x * v.x + v.y * v.y + v.z * v.z + v.w * v.w;
#pragma unroll
    for (int off = 32; off; off >>= 1) ss += __shfl_down(ss, off);
    __shared__ float partial[4];
    __shared__ float s_inv;
    if ((tid & 63) == 0) partial[tid >> 6] = ss;
    __syncthreads();
    if (tid == 0)
        s_inv = rsqrtf((partial[0] + partial[1] + partial[2] + partial[3]) * (1.0f / H) + EPS);
    __syncthreads();
    float inv = s_inv;
    float4 wv = ((const float4*)ln2w)[tid];
    float4 o;
    o.x = v.x * wv.x * inv; o.y = v.y * wv.y * inv;
    o.z = v.z * wv.z * inv; o.w = v.w * wv.w * inv;
    ushort4 ob;
    ob.x = f2bf(o.x); ob.y = f2bf(o.y); ob.z = f2bf(o.z); ob.w = f2bf(o.w);
    ((ushort4*)(x2bf + (size_t)t * H))[tid] = ob;

    const float4* wr = (const float4*)(w_router + (size_t)tid * 4 * E_);
    float p[E_];
    {
        float4 r0a = wr[0], r0b = wr[1];
        float4 r1a = wr[2], r1b = wr[3];
        float4 r2a = wr[4], r2b = wr[5];
        float4 r3a = wr[6], r3b = wr[7];
        p[0] = o.x * r0a.x + o.y * r1a.x + o.z * r2a.x + o.w * r3a.x;
        p[1] = o.x * r0a.y + o.y * r1a.y + o.z * r2a.y + o.w * r3a.y;
        p[2] = o.x * r0a.z + o.y * r1a.z + o.z * r2a.z + o.w * r3a.z;
        p[3] = o.x * r0a.w + o.y * r1a.w + o.z * r2a.w + o.w * r3a.w;
        p[4] = o.x * r0b.x + o.y * r1b.x + o.z * r2b.x + o.w * r3b.x;
        p[5] = o.x * r0b.y + o.y * r1b.y + o.z * r2b.y + o.w * r3b.y;
        p[6] = o.x * r0b.z + o.y * r1b.z + o.z * r2b.z + o.w * r3b.z;
        p[7] = o.x * r0b.w + o.y * r1b.w + o.z * r2b.w + o.w * r3b.w;
    }
    __shared__ float wsum[4][E_];
    int wv2 = tid >> 6, lane = tid & 63;
#pragma unroll
    for (int e = 0; e < E_; e++) {
        float r = p[e];
#pragma unroll
        for (int off = 32; off; off >>= 1) r += __shfl_xor(r, off);
        if (lane == 0) wsum[wv2][e] = r;
    }
    __syncthreads();
    __shared__ float logits[E_];
    if (tid < E_)
        logits[tid] = wsum[0][tid] + wsum[1][tid] + wsum[2][tid] + wsum[3][tid] + b_router[tid];
    __syncthreads();
    if (tid == 0) {
        int i0 = 0; float v0 = logits[0];
        for (int ee = 1; ee < E_; ee++)
            if (logits[ee] > v0) { v0 = logits[ee]; i0 = ee; }
        int i1 = -1; float v1 = -3.4e38f;
        for (int ee = 0; ee < E_; ee++)
            if (ee != i0 && logits[ee] > v1) { v1 = logits[ee]; i1 = ee; }
        float w0 = 1.0f / (1.0f + __expf(v1 - v0));
        ridx[t * 2] = i0; ridx[t * 2 + 1] = i1;
        rwt[t * 2] = w0;  rwt[t * 2 + 1] = 1.0f - w0;
        atomicAdd(&cnt[i0], 1);
        atomicAdd(&cnt[i1], 1);
    }
}

// ---------------- plumb: offsets + scatter in one 1-block kernel ----------------
__global__ __launch_bounds__(256) void plumb_kernel(const int* __restrict__ cnt,
                                                    const int* __restrict__ ridx,
                                                    int* __restrict__ poff,
                                                    int* __restrict__ list) {
    __shared__ int lpos[E_], lpoff[E_];
    int tid = threadIdx.x;
    if (tid == 0) {
        int run = 0;
        for (int e = 0; e < E_; e++) { lpoff[e] = run; poff[e] = run; run += (cnt[e] + 63) & ~63; }
    }
    if (tid < E_) lpos[tid] = 0;
    __syncthreads();
    for (int i = tid; i < 2 * T_; i += 256) {
        int e = ridx[i];
        int pp = atomicAdd(&lpos[e], 1);
        list[lpoff[e] + pp] = i;
    }
}

// ---------------- tiled grouped gate_up GEMM + swiglu ----------------
// BM=128 (4 waves x 32 rows, MF=2), BN=32 interleaved gu-cols (=16 f cols), BK=64 dbuf LDS.
// grid: x = 2048/32 = 64, y = e*8 + tl (early exit)
__global__ __launch_bounds__(256) void moe_gateup_t(const unsigned short* __restrict__ x2bf,
                                                    const int* __restrict__ list,
                                                    const int* __restrict__ cnt,
                                                    const int* __restrict__ poff,
                                                    const float* __restrict__ wgu,
                                                    const float* __restrict__ bgu,
                                                    unsigned short* __restrict__ act_bf) {
    int e = blockIdx.y >> 3, tl = blockIdx.y & 7;
    int n = cnt[e];
    if (tl * 128 >= n) return;
    int base = poff[e];
    int nb = blockIdx.x;
    int tid = threadIdx.x;
    int w = tid >> 6, lane = tid & 63;
    int r16 = lane & 15, kq = lane >> 4;
    int skb = tid >> 5, sn = tid & 31;

    __shared__ unsigned short Wt[2][8][32][8];

    const float* wsrc = wgu + (size_t)e * (1024 * 2048) + (size_t)(skb * 8) * 2048 + nb * 32 + sn;

    const unsigned short* ap[2];
#pragma unroll
    for (int mf = 0; mf < 2; mf++) {
        int rr = tl * 128 + w * 32 + mf * 16 + r16;
        int t2 = (rr < n) ? list[base + rr] : list[base];
        ap[mf] = x2bf + (size_t)(t2 >> 1) * 1024 + kq * 8;
    }

    f32x4 acc[2][2] = {};
    float wr[8];
#pragma unroll
    for (int j = 0; j < 8; j++) wr[j] = wsrc[(size_t)j * 2048];
    {
        s16x8 p;
#pragma unroll
        for (int j = 0; j < 8; j++) p[j] = (short)f2bf(wr[j]);
        *(s16x8*)&Wt[0][skb][sn][0] = p;
    }
    __syncthreads();

#pragma unroll 2
    for (int t = 0; t < 16; t++) {
        s16x8 af[2][2];
#pragma unroll
        for (int mf = 0; mf < 2; mf++)
#pragma unroll
            for (int ks = 0; ks < 2; ks++)
                af[mf][ks] = *(const s16x8*)(ap[mf] + t * 64 + ks * 32);
        if (t < 15) {
            const float* ws = wsrc + (size_t)(t + 1) * 64 * 2048;
#pragma unroll
            for (int j = 0; j < 8; j++) wr[j] = ws[(size_t)j * 2048];
        }
#pragma unroll
        for (int ks = 0; ks < 2; ks++) {
            s16x8 b0 = *(const s16x8*)&Wt[t & 1][ks * 4 + kq][r16][0];
            s16x8 b1 = *(const s16x8*)&Wt[t & 1][ks * 4 + kq][16 + r16][0];
#pragma unroll
            for (int mf = 0; mf < 2; mf++) {
                acc[mf][0] = __builtin_amdgcn_mfma_f32_16x16x32_bf16(af[mf][ks], b0, acc[mf][0], 0, 0, 0);
                acc[mf][1] = __builtin_amdgcn_mfma_f32_16x16x32_bf16(af[mf][ks], b1, acc[mf][1], 0, 0, 0);
            }
        }
        if (t < 15) {
            s16x8 p;
#pragma unroll
            for (int j = 0; j < 8; j++) p[j] = (short)f2bf(wr[j]);
            *(s16x8*)&Wt[(t & 1) ^ 1][skb][sn][0] = p;
        }
        __syncthreads();
    }

    // epilogue: gate on even gu-cols, up on odd; pair via shfl_xor lane^1
    int parity = r16 & 1;
#pragma unroll
    for (int mf = 0; mf < 2; mf++)
#pragma unroll
        for (int nf = 0; nf < 2; nf++) {
            int gucol = nb * 32 + nf * 16 + r16;
            float bb = bgu[(size_t)e * 2048 + gucol];
#pragma unroll
            for (int r = 0; r < 4; r++) {
                float v = acc[mf][nf][r] + bb;
                float o = __shfl_xor(v, 1);
                if (!parity) {
                    float g = fminf(v, LIMIT);
                    float u = fminf(fmaxf(o, -LIMIT), LIMIT);
                    float glu = g / (1.0f + __expf(-ALPHA * g));
                    int rr = tl * 128 + w * 32 + mf * 16 + kq * 4 + r;
                    if (rr < n)
                        act_bf[(size_t)(base + rr) * FFN + (gucol >> 1)] = f2bf((u + 1.0f) * glu);
                }
            }
        }
}

// ---------------- tiled grouped down GEMM, split-K z=2, atomicAdd epilogue ----------------
// BM=128 (MF=2), BN=32, BK=64 dbuf. grid: x = 1024/32 = 32, y = e*8+tl, z = 2 (K halves)
__global__ __launch_bounds__(256) void moe_down_t(const unsigned short* __restrict__ act_bf,
                                                  const int* __restrict__ list,
                                                  const int* __restrict__ cnt,
                                                  const int* __restrict__ poff,
                                                  const float* __restrict__ rwt,
                                                  const float* __restrict__ wdn,
                                                  const float* __restrict__ b_down,
                                                  float* __restrict__ out) {
    int e = blockIdx.y >> 3, tl = blockIdx.y & 7;
    int n = cnt[e];
    if (tl * 128 >= n) return;
    int base = poff[e];
    int nb = blockIdx.x;
    int z  = blockIdx.z;
    int tid = threadIdx.x;
    int w = tid >> 6, lane = tid & 63;
    int r16 = lane & 15, kq = lane >> 4;
    int skb = tid >> 5, sn = tid & 31;

    __shared__ unsigned short Wt[2][8][32][8];

    const float* wsrc = wdn + (size_t)e * (1024 * 1024) + (size_t)(z * 512 + skb * 8) * 1024 + nb * 32 + sn;
    const unsigned short* ap[2];
#pragma unroll
    for (int mf = 0; mf < 2; mf++)
        ap[mf] = act_bf + (size_t)(base + tl * 128 + w * 32 + mf * 16 + r16) * 1024 + z * 512 + kq * 8;

    f32x4 acc[2][2] = {};
    float wr[8];
#pragma unroll
    for (int j = 0; j < 8; j++) wr[j] = wsrc[(size_t)j * 1024];
    {
        s16x8 p;
#pragma unroll
        for (int j = 0; j < 8; j++) p[j] = (short)f2bf(wr[j]);
        *(s16x8*)&Wt[0][skb][sn][0] = p;
    }
    __syncthreads();

#pragma unroll 2
    for (int t = 0; t < 8; t++) {
        s16x8 af[2][2];
#pragma unroll
        for (int mf = 0; mf < 2; mf++)
#pragma unroll
            for (int ks = 0; ks < 2; ks++)
                af[mf][ks] = *(const s16x8*)(ap[mf] + t * 64 + ks * 32);
        if (t < 7) {
            const float* ws = wsrc + (size_t)(t + 1) * 64 * 1024;
#pragma unroll
            for (int j = 0; j < 8; j++) wr[j] = ws[(size_t)j * 1024];
        }
#pragma unroll
        for (int ks = 0; ks < 2; ks++) {
            s16x8 b0 = *(const s16x8*)&Wt[t & 1][ks * 4 + kq][r16][0];
            s16x8 b1 = *(const s16x8*)&Wt[t & 1][ks * 4 + kq][16 + r16][0];
#pragma unroll
            for (int mf = 0; mf < 2; mf++) {
                acc[mf][0] = __builtin_amdgcn_mfma_f32_16x16x32_bf16(af[mf][ks], b0, acc[mf][0], 0, 0, 0);
                acc[mf][1] = __builtin_amdgcn_mfma_f32_16x16x32_bf16(af[mf][ks], b1, acc[mf][1], 0, 0, 0);
            }
        }
        if (t < 7) {
            s16x8 p;
#pragma unroll
            for (int j = 0; j < 8; j++) p[j] = (short)f2bf(wr[j]);
            *(s16x8*)&Wt[(t & 1) ^ 1][skb][sn][0] = p;
        }
        __syncthreads();
    }

#pragma unroll
    for (int mf = 0; mf < 2; mf++)
#pragma unroll
        for (int r = 0; r < 4; r++) {
            int rr = tl * 128 + w * 32 + mf * 16 + kq * 4 + r;
            if (rr < n) {
                int t2 = list[base + rr];
                float sc = rwt[t2];
                float* op = out + (size_t)(t2 >> 1) * H;
#pragma unroll
                for (int nf = 0; nf < 2; nf++) {
                    int col = nb * 32 + nf * 16 + r16;
                    float v = acc[mf][nf][r] + (z == 0 ? b_down[(size_t)e * 1024 + col] : 0.0f);
                    atomicAdd(op + col, sc * v);
                }
            }
        }
}

extern "C" void kernel_launch(void* const* d_in, const int* in_sizes, int n_in,
                              void* d_out, int out_size, void* d_ws, size_t ws_size,
                              hipStream_t stream) {
    const float* hidden          = (const float*)d_in[0];
    const float* kv_cache        = (const float*)d_in[1];
    const int*   kv_page_indices = (const int*)d_in[3];
    const float* sinks           = (const float*)d_in[4];
    const float* w_qkv           = (const float*)d_in[5];
    const float* b_qkv           = (const float*)d_in[6];
    const float* w_o             = (const float*)d_in[7];
    const float* b_o             = (const float*)d_in[8];
    const float* ln1_w           = (const float*)d_in[9];
    const float* ln2_w           = (const float*)d_in[10];
    const float* w_router        = (const float*)d_in[11];
    const float* b_router        = (const float*)d_in[12];
    const float* w_gate_up       = (const float*)d_in[13];
    const float* b_gate_up       = (const float*)d_in[14];
    const float* w_down          = (const float*)d_in[15];
    const float* b_down          = (const float*)d_in[16];
    float* out = (float*)d_out;

    // ---- workspace layout ----
    char* base = (char*)d_ws;
    float* qkv   = (float*)base;                       base += (size_t)T_ * QKV_N * 4;
    float* hbuf  = (float*)base;                       base += (size_t)T_ * H * 4;
    unsigned short* x_bf    = (unsigned short*)base;   base += (size_t)T_ * H * 2;
    unsigned short* x2_bf   = (unsigned short*)base;   base += (size_t)T_ * H * 2;
    unsigned short* attn_bf = (unsigned short*)base;   base += (size_t)T_ * NQ * HD * 2;
    unsigned short* act_bf  = (unsigned short*)base;   base += (size_t)(MAXROWS + 128) * FFN * 2;
    float* rwt  = (float*)base;                        base += 2 * T_ * 4;
    int*   ridx = (int*)base;                          base += 2 * T_ * 4;
    int*   cnt  = (int*)base;                          base += E_ * 4;
    int*   poff = (int*)base;                          base += E_ * 4;
    int*   list = (int*)base;                          base += MAXROWS * 4;

    rmsnorm_kernel<<<T_, 256, 0, stream>>>(hidden, ln1_w, x_bf, cnt);
    gemm_dense_t<<<dim3(QKV_N / 32, T_ / 64), 256, 0, stream>>>(
        x_bf, w_qkv, b_qkv, nullptr, qkv, nullptr, QKV_N);
    attn_group_kernel<<<B_ * Q_ * NKV, 256, 0, stream>>>(qkv, kv_cache, kv_page_indices, sinks, attn_bf);
    gemm_dense_t<<<dim3(H / 32, T_ / 64), 256, 0, stream>>>(
        attn_bf, w_o, b_o, hidden, hbuf, out, H);
    rms_router_kernel<<<T_, 256, 0, stream>>>(hbuf, ln2_w, w_router, b_router,
                                              x2_bf, ridx, rwt, cnt);
    plumb_kernel<<<1, 256, 0, stream>>>(cnt, ridx, poff, list);
    moe_gateup_t<<<dim3(FFN * 2 / 32, E_ * 8), 256, 0, stream>>>(
        x2_bf, list, cnt, poff, w_gate_up, b_gate_up, act_bf);
    moe_down_t<<<dim3(H / 32, E_ * 8, 2), 256, 0, stream>>>(
        act_bf, list, cnt, poff, rwt, w_down, b_down, out);
}

// Round 4
// 290.311 us; speedup vs baseline: 1.1552x; 1.1552x over previous
//
#include <hip/hip_runtime.h>

// ---- static config (mirrors reference) ----
constexpr int H    = 1024;
constexpr int HD   = 64;
constexpr int NQ   = 16;
constexpr int NKV  = 4;
constexpr int E_   = 8;
constexpr int FFN  = 1024;
constexpr int B_   = 4;
constexpr int Q_   = 128;
constexpr int P_   = 8;
constexpr int PS   = 128;
constexpr int S_   = P_ * PS;                 // 1024
constexpr int T_   = B_ * Q_;                 // 512
constexpr int QKV_N = HD * (NQ + 2 * NKV);    // 1536
constexpr float EPS   = 1e-5f;
constexpr float ALPHA = 1.702f;
constexpr float LIMIT = 7.0f;
constexpr float SCALE = 0.125f;               // HD^-0.5

constexpr int MAXROWS = 1536;                 // 1024 assignments + per-expert pad to 64

typedef __attribute__((ext_vector_type(4))) float f32x4;
typedef __attribute__((ext_vector_type(8))) short s16x8;

__device__ __forceinline__ unsigned short f2bf(float f) {
    unsigned u = __float_as_uint(f);
    u += 0x7FFFu + ((u >> 16) & 1u);
    return (unsigned short)(u >> 16);
}

// ---------------- RMSNorm -> bf16 out (also zeroes cnt once) ----------------
__global__ __launch_bounds__(256) void rmsnorm_kernel(const float* __restrict__ in,
                                                      const float* __restrict__ w,
                                                      unsigned short* __restrict__ outb,
                                                      int* __restrict__ cnt) {
    int t   = blockIdx.x;
    int tid = threadIdx.x;
    if (t == 0 && tid < E_) cnt[tid] = 0;
    float4 v = ((const float4*)(in + (size_t)t * H))[tid];
    float ss = v.x * v.x + v.y * v.y + v.z * v.z + v.w * v.w;
#pragma unroll
    for (int off = 32; off; off >>= 1) ss += __shfl_down(ss, off);
    __shared__ float partial[4];
    __shared__ float s_inv;
    if ((tid & 63) == 0) partial[tid >> 6] = ss;
    __syncthreads();
    if (tid == 0)
        s_inv = rsqrtf((partial[0] + partial[1] + partial[2] + partial[3]) * (1.0f / H) + EPS);
    __syncthreads();
    float inv = s_inv;
    float4 wv = ((const float4*)w)[tid];
    ushort4 ob;
    ob.x = f2bf(v.x * wv.x * inv); ob.y = f2bf(v.y * wv.y * inv);
    ob.z = f2bf(v.z * wv.z * inv); ob.w = f2bf(v.w * wv.w * inv);
    ((ushort4*)(outb + (size_t)t * H))[tid] = ob;
}

// ---------------- tiled dense GEMM: A bf16 [M][1024] x W f32 [1024][N] ----------------
// BM=64 (4 waves x 16 rows), BN=32, BK=64; pipelined: W 2-deep, A 1-deep, 1 barrier/iter.
__global__ __launch_bounds__(256) void gemm_dense_t(const unsigned short* __restrict__ Abf,
                                                    const float* __restrict__ W,
                                                    const float* __restrict__ bias,
                                                    const float* __restrict__ resid,
                                                    float* __restrict__ C,
                                                    float* __restrict__ Cdup, int N) {
    int nb = blockIdx.x, mb = blockIdx.y * 64;
    int tid = threadIdx.x;
    int w = tid >> 6, lane = tid & 63;
    int r16 = lane & 15, kq = lane >> 4;
    int skb = tid >> 5, sn = tid & 31;

    __shared__ unsigned short Wt[2][8][32][8];

    size_t sN = (size_t)N;
    const float* wsrc = W + (size_t)(skb * 8) * sN + nb * 32 + sn;
    const unsigned short* ap = Abf + (size_t)(mb + w * 16 + r16) * 1024 + kq * 8;

    float wr[2][8];
    s16x8 af[2][2];
    f32x4 acc[2] = {};

#pragma unroll
    for (int j = 0; j < 8; j++) wr[0][j] = wsrc[(size_t)j * sN];
    {
        s16x8 p;
#pragma unroll
        for (int j = 0; j < 8; j++) p[j] = (short)f2bf(wr[0][j]);
        *(s16x8*)&Wt[0][skb][sn][0] = p;
    }
#pragma unroll
    for (int j = 0; j < 8; j++) wr[1][j] = wsrc[(size_t)(64 + j) * sN];
#pragma unroll
    for (int ks = 0; ks < 2; ks++) af[0][ks] = *(const s16x8*)(ap + ks * 32);
    __syncthreads();

#pragma unroll
    for (int t = 0; t < 16; t++) {
        s16x8 b0[2], b1[2];
#pragma unroll
        for (int ks = 0; ks < 2; ks++) {
            b0[ks] = *(const s16x8*)&Wt[t & 1][ks * 4 + kq][r16][0];
            b1[ks] = *(const s16x8*)&Wt[t & 1][ks * 4 + kq][16 + r16][0];
        }
        if (t < 15) {
#pragma unroll
            for (int ks = 0; ks < 2; ks++)
                af[(t + 1) & 1][ks] = *(const s16x8*)(ap + (t + 1) * 64 + ks * 32);
        }
        if (t < 14) {
#pragma unroll
            for (int j = 0; j < 8; j++) wr[t & 1][j] = wsrc[(size_t)((t + 2) * 64 + j) * sN];
        }
#pragma unroll
        for (int ks = 0; ks < 2; ks++) {
            acc[0] = __builtin_amdgcn_mfma_f32_16x16x32_bf16(af[t & 1][ks], b0[ks], acc[0], 0, 0, 0);
            acc[1] = __builtin_amdgcn_mfma_f32_16x16x32_bf16(af[t & 1][ks], b1[ks], acc[1], 0, 0, 0);
        }
        if (t < 15) {
            s16x8 p;
#pragma unroll
            for (int j = 0; j < 8; j++) p[j] = (short)f2bf(wr[(t + 1) & 1][j]);
            *(s16x8*)&Wt[(t + 1) & 1][skb][sn][0] = p;
        }
        __syncthreads();
    }

    int row0 = mb + w * 16 + kq * 4;
#pragma unroll
    for (int nf = 0; nf < 2; nf++) {
        int col = nb * 32 + nf * 16 + r16;
        float bcol = bias[col];
#pragma unroll
        for (int r = 0; r < 4; r++) {
            int row = row0 + r;
            float v = acc[nf][r] + bcol;
            if (resid) v += resid[(size_t)row * sN + col];
            C[(size_t)row * sN + col] = v;
            if (Cdup) Cdup[(size_t)row * sN + col] = v;
        }
    }
}

// ---------------- Attention: one block per (b, q, kvh); 4 heads/block; bf16 out ----------------
__global__ __launch_bounds__(256) void attn_group_kernel(const float* __restrict__ qkv,
                                                         const float* __restrict__ kv_cache,
                                                         const int* __restrict__ page_idx,
                                                         const float* __restrict__ sinks,
                                                         unsigned short* __restrict__ attn_bf) {
    int blk = blockIdx.x;
    int kvh = blk & 3;
    int q   = (blk >> 2) & 127;
    int b   = blk >> 9;
    int t   = b * Q_ + q;
    int tid = threadIdx.x;
    int s_lo = S_ - Q_ - 127 + q;

    __shared__ __align__(16) float Vs[128][64];
    __shared__ __align__(16) float qs4[4][64];
    __shared__ float pv[4][128];
    __shared__ float sD[4];

#pragma unroll
    for (int r = 0; r < 8; r++) {
        int l = r * 256 + tid;
        int key = l >> 4, c = l & 15;
        int s = s_lo + key;
        const float* vp;
        if (s < S_ - Q_) {
            int page = page_idx[b * P_ + (s >> 7)];
            vp = kv_cache + (size_t)page * 65536 + 32768 + (size_t)(s & 127) * (NKV * HD) + kvh * HD;
        } else {
            vp = qkv + (size_t)(b * Q_ + (s - (S_ - Q_))) * QKV_N + (NQ + NKV) * HD + kvh * HD;
        }
        ((float4*)Vs[key])[c] = *(const float4*)(vp + c * 4);
    }
    {
        int hh = tid >> 6, d2 = tid & 63;
        qs4[hh][d2] = qkv[(size_t)t * QKV_N + (kvh * 4 + hh) * HD + d2];
    }
    __syncthreads();

    {
        int key = tid & 127, hp = tid >> 7;
        int s = s_lo + key;
        const float* kp;
        if (s < S_ - Q_) {
            int page = page_idx[b * P_ + (s >> 7)];
            kp = kv_cache + (size_t)page * 65536 + (size_t)(s & 127) * (NKV * HD) + kvh * HD;
        } else {
            kp = qkv + (size_t)(b * Q_ + (s - (S_ - Q_))) * QKV_N + NQ * HD + kvh * HD;
        }
        const float4* kp4 = (const float4*)kp;
        const float4* q0p = (const float4*)qs4[hp * 2];
        const float4* q1p = (const float4*)qs4[hp * 2 + 1];
        float sc0 = 0.f, sc1 = 0.f;
#pragma unroll
        for (int d4 = 0; d4 < 16; d4++) {
            float4 kk = kp4[d4];
            float4 q0 = q0p[d4], q1 = q1p[d4];
            sc0 += q0.x * kk.x + q0.y * kk.y + q0.z * kk.z + q0.w * kk.w;
            sc1 += q1.x * kk.x + q1.y * kk.y + q1.z * kk.z + q1.w * kk.w;
        }
        pv[hp * 2][key]     = sc0 * SCALE;
        pv[hp * 2 + 1][key] = sc1 * SCALE;
    }
    __syncthreads();

    {
        int wv = tid >> 6, lane = tid & 63;
        float a0 = pv[wv][lane], a1 = pv[wv][lane + 64];
        float m = fmaxf(a0, a1);
#pragma unroll
        for (int off = 32; off; off >>= 1) m = fmaxf(m, __shfl_xor(m, off));
        float p0 = __expf(a0 - m), p1 = __expf(a1 - m);
        float l = p0 + p1;
#pragma unroll
        for (int off = 32; off; off >>= 1) l += __shfl_xor(l, off);
        pv[wv][lane] = p0;
        pv[wv][lane + 64] = p1;
        if (lane == 0) sD[wv] = l + __expf(sinks[kvh * 4 + wv] - m);
    }
    __syncthreads();

    {
        int hh = tid >> 6, d2 = tid & 63;
        float a0 = 0.f, a1 = 0.f, a2 = 0.f, a3 = 0.f;
#pragma unroll 4
        for (int i = 0; i < 128; i += 4) {
            a0 += pv[hh][i]     * Vs[i][d2];
            a1 += pv[hh][i + 1] * Vs[i + 1][d2];
            a2 += pv[hh][i + 2] * Vs[i + 2][d2];
            a3 += pv[hh][i + 3] * Vs[i + 3][d2];
        }
        float acc = ((a0 + a1) + (a2 + a3)) / sD[hh];
        attn_bf[(size_t)t * (NQ * HD) + (kvh * 4 + hh) * HD + d2] = f2bf(acc);
    }
}

// ---------------- fused RMSNorm2 + router ----------------
__global__ __launch_bounds__(256) void rms_router_kernel(const float* __restrict__ hbuf,
                                                         const float* __restrict__ ln2w,
                                                         const float* __restrict__ w_router,
                                                         const float* __restrict__ b_router,
                                                         unsigned short* __restrict__ x2bf,
                                                         int* __restrict__ ridx,
                                                         float* __restrict__ rwt,
                                                         int* __restrict__ cnt) {
    int t = blockIdx.x;
    int tid = threadIdx.x;
    float4 v = ((const float4*)(hbuf + (size_t)t * H))[tid];
    float ss = v.x * v.x + v.y * v.y + v.z * v.z + v.w * v.w;
#pragma unroll
    for (int off = 32; off; off >>= 1) ss += __shfl_down(ss, off);
    __shared__ float partial[4];
    __shared__ float s_inv;
    if ((tid & 63) == 0) partial[tid >> 6] = ss;
    __syncthreads();
    if (tid == 0)
        s_inv = rsqrtf((partial[0] + partial[1] + partial[2] + partial[3]) * (1.0f / H) + EPS);
    __syncthreads();
    float inv = s_inv;
    float4 wv = ((const float4*)ln2w)[tid];
    float4 o;
    o.x = v.x * wv.x * inv; o.y = v.y * wv.y * inv;
    o.z = v.z * wv.z * inv; o.w = v.w * wv.w * inv;
    ushort4 ob;
    ob.x = f2bf(o.x); ob.y = f2bf(o.y); ob.z = f2bf(o.z); ob.w = f2bf(o.w);
    ((ushort4*)(x2bf + (size_t)t * H))[tid] = ob;

    const float4* wr = (const float4*)(w_router + (size_t)tid * 4 * E_);
    float p[E_];
    {
        float4 r0a = wr[0], r0b = wr[1];
        float4 r1a = wr[2], r1b = wr[3];
        float4 r2a = wr[4], r2b = wr[5];
        float4 r3a = wr[6], r3b = wr[7];
        p[0] = o.x * r0a.x + o.y * r1a.x + o.z * r2a.x + o.w * r3a.x;
        p[1] = o.x * r0a.y + o.y * r1a.y + o.z * r2a.y + o.w * r3a.y;
        p[2] = o.x * r0a.z + o.y * r1a.z + o.z * r2a.z + o.w * r3a.z;
        p[3] = o.x * r0a.w + o.y * r1a.w + o.z * r2a.w + o.w * r3a.w;
        p[4] = o.x * r0b.x + o.y * r1b.x + o.z * r2b.x + o.w * r3b.x;
        p[5] = o.x * r0b.y + o.y * r1b.y + o.z * r2b.y + o.w * r3b.y;
        p[6] = o.x * r0b.z + o.y * r1b.z + o.z * r2b.z + o.w * r3b.z;
        p[7] = o.x * r0b.w + o.y * r1b.w + o.z * r2b.w + o.w * r3b.w;
    }
    __shared__ float wsum[4][E_];
    int wv2 = tid >> 6, lane = tid & 63;
#pragma unroll
    for (int e = 0; e < E_; e++) {
        float r = p[e];
#pragma unroll
        for (int off = 32; off; off >>= 1) r += __shfl_xor(r, off);
        if (lane == 0) wsum[wv2][e] = r;
    }
    __syncthreads();
    __shared__ float logits[E_];
    if (tid < E_)
        logits[tid] = wsum[0][tid] + wsum[1][tid] + wsum[2][tid] + wsum[3][tid] + b_router[tid];
    __syncthreads();
    if (tid == 0) {
        int i0 = 0; float v0 = logits[0];
        for (int ee = 1; ee < E_; ee++)
            if (logits[ee] > v0) { v0 = logits[ee]; i0 = ee; }
        int i1 = -1; float v1 = -3.4e38f;
        for (int ee = 0; ee < E_; ee++)
            if (ee != i0 && logits[ee] > v1) { v1 = logits[ee]; i1 = ee; }
        float w0 = 1.0f / (1.0f + __expf(v1 - v0));
        ridx[t * 2] = i0; ridx[t * 2 + 1] = i1;
        rwt[t * 2] = w0;  rwt[t * 2 + 1] = 1.0f - w0;
        atomicAdd(&cnt[i0], 1);
        atomicAdd(&cnt[i1], 1);
    }
}

// ---------------- plumb: offsets + scatter in one 1-block kernel ----------------
__global__ __launch_bounds__(256) void plumb_kernel(const int* __restrict__ cnt,
                                                    const int* __restrict__ ridx,
                                                    int* __restrict__ poff,
                                                    int* __restrict__ list) {
    __shared__ int lpos[E_], lpoff[E_];
    int tid = threadIdx.x;
    if (tid == 0) {
        int run = 0;
        for (int e = 0; e < E_; e++) { lpoff[e] = run; poff[e] = run; run += (cnt[e] + 63) & ~63; }
    }
    if (tid < E_) lpos[tid] = 0;
    __syncthreads();
    for (int i = tid; i < 2 * T_; i += 256) {
        int e = ridx[i];
        int pp = atomicAdd(&lpos[e], 1);
        list[lpoff[e] + pp] = i;
    }
}

// ---------------- tiled grouped gate_up GEMM + swiglu ----------------
// BM=64 (4 waves x 16 rows), BN=32 interleaved gu-cols (=16 f cols), BK=64, pipelined.
// grid: x = 2048/32 = 64, y = E*16 (64-row tiles, early exit)
__global__ __launch_bounds__(256) void moe_gateup_t(const unsigned short* __restrict__ x2bf,
                                                    const int* __restrict__ list,
                                                    const int* __restrict__ cnt,
                                                    const int* __restrict__ poff,
                                                    const float* __restrict__ wgu,
                                                    const float* __restrict__ bgu,
                                                    unsigned short* __restrict__ act_bf) {
    int e = blockIdx.y >> 4, tl = blockIdx.y & 15;
    int n = cnt[e];
    if (tl * 64 >= n) return;
    int base = poff[e];
    int nb = blockIdx.x;
    int tid = threadIdx.x;
    int w = tid >> 6, lane = tid & 63;
    int r16 = lane & 15, kq = lane >> 4;
    int skb = tid >> 5, sn = tid & 31;

    __shared__ unsigned short Wt[2][8][32][8];

    const float* wsrc = wgu + (size_t)e * (1024 * 2048) + (size_t)(skb * 8) * 2048 + nb * 32 + sn;
    int rr0 = tl * 64 + w * 16 + r16;
    int t2a = (rr0 < n) ? list[base + rr0] : list[base];
    const unsigned short* ap = x2bf + (size_t)(t2a >> 1) * 1024 + kq * 8;

    float wr[2][8];
    s16x8 af[2][2];
    f32x4 acc[2] = {};

#pragma unroll
    for (int j = 0; j < 8; j++) wr[0][j] = wsrc[(size_t)j * 2048];
    {
        s16x8 p;
#pragma unroll
        for (int j = 0; j < 8; j++) p[j] = (short)f2bf(wr[0][j]);
        *(s16x8*)&Wt[0][skb][sn][0] = p;
    }
#pragma unroll
    for (int j = 0; j < 8; j++) wr[1][j] = wsrc[(size_t)(64 + j) * 2048];
#pragma unroll
    for (int ks = 0; ks < 2; ks++) af[0][ks] = *(const s16x8*)(ap + ks * 32);
    __syncthreads();

#pragma unroll
    for (int t = 0; t < 16; t++) {
        s16x8 b0[2], b1[2];
#pragma unroll
        for (int ks = 0; ks < 2; ks++) {
            b0[ks] = *(const s16x8*)&Wt[t & 1][ks * 4 + kq][r16][0];
            b1[ks] = *(const s16x8*)&Wt[t & 1][ks * 4 + kq][16 + r16][0];
        }
        if (t < 15) {
#pragma unroll
            for (int ks = 0; ks < 2; ks++)
                af[(t + 1) & 1][ks] = *(const s16x8*)(ap + (t + 1) * 64 + ks * 32);
        }
        if (t < 14) {
#pragma unroll
            for (int j = 0; j < 8; j++) wr[t & 1][j] = wsrc[(size_t)((t + 2) * 64 + j) * 2048];
        }
#pragma unroll
        for (int ks = 0; ks < 2; ks++) {
            acc[0] = __builtin_amdgcn_mfma_f32_16x16x32_bf16(af[t & 1][ks], b0[ks], acc[0], 0, 0, 0);
            acc[1] = __builtin_amdgcn_mfma_f32_16x16x32_bf16(af[t & 1][ks], b1[ks], acc[1], 0, 0, 0);
        }
        if (t < 15) {
            s16x8 p;
#pragma unroll
            for (int j = 0; j < 8; j++) p[j] = (short)f2bf(wr[(t + 1) & 1][j]);
            *(s16x8*)&Wt[(t + 1) & 1][skb][sn][0] = p;
        }
        __syncthreads();
    }

    // epilogue: gate on even gu-cols, up on odd; pair via shfl_xor lane^1
    int parity = r16 & 1;
#pragma unroll
    for (int nf = 0; nf < 2; nf++) {
        int gucol = nb * 32 + nf * 16 + r16;
        float bb = bgu[(size_t)e * 2048 + gucol];
#pragma unroll
        for (int r = 0; r < 4; r++) {
            float v = acc[nf][r] + bb;
            float o = __shfl_xor(v, 1);
            if (!parity) {
                float g = fminf(v, LIMIT);
                float u = fminf(fmaxf(o, -LIMIT), LIMIT);
                float glu = g / (1.0f + __expf(-ALPHA * g));
                int rr = tl * 64 + w * 16 + kq * 4 + r;
                if (rr < n)
                    act_bf[(size_t)(base + rr) * FFN + (gucol >> 1)] = f2bf((u + 1.0f) * glu);
            }
        }
    }
}

// ---------------- tiled grouped down GEMM, split-K z=2, atomicAdd epilogue ----------------
// BM=64, BN=32, BK=64, pipelined. grid: x = 1024/32 = 32, y = E*16, z = 2 (K halves)
__global__ __launch_bounds__(256) void moe_down_t(const unsigned short* __restrict__ act_bf,
                                                  const int* __restrict__ list,
                                                  const int* __restrict__ cnt,
                                                  const int* __restrict__ poff,
                                                  const float* __restrict__ rwt,
                                                  const float* __restrict__ wdn,
                                                  const float* __restrict__ b_down,
                                                  float* __restrict__ out) {
    int e = blockIdx.y >> 4, tl = blockIdx.y & 15;
    int n = cnt[e];
    if (tl * 64 >= n) return;
    int base = poff[e];
    int nb = blockIdx.x;
    int z  = blockIdx.z;
    int tid = threadIdx.x;
    int w = tid >> 6, lane = tid & 63;
    int r16 = lane & 15, kq = lane >> 4;
    int skb = tid >> 5, sn = tid & 31;

    __shared__ unsigned short Wt[2][8][32][8];

    const float* wsrc = wdn + (size_t)e * (1024 * 1024) + (size_t)(z * 512 + skb * 8) * 1024 + nb * 32 + sn;
    const unsigned short* ap = act_bf + (size_t)(base + tl * 64 + w * 16 + r16) * 1024 + z * 512 + kq * 8;

    float wr[2][8];
    s16x8 af[2][2];
    f32x4 acc[2] = {};

#pragma unroll
    for (int j = 0; j < 8; j++) wr[0][j] = wsrc[(size_t)j * 1024];
    {
        s16x8 p;
#pragma unroll
        for (int j = 0; j < 8; j++) p[j] = (short)f2bf(wr[0][j]);
        *(s16x8*)&Wt[0][skb][sn][0] = p;
    }
#pragma unroll
    for (int j = 0; j < 8; j++) wr[1][j] = wsrc[(size_t)(64 + j) * 1024];
#pragma unroll
    for (int ks = 0; ks < 2; ks++) af[0][ks] = *(const s16x8*)(ap + ks * 32);
    __syncthreads();

#pragma unroll
    for (int t = 0; t < 8; t++) {
        s16x8 b0[2], b1[2];
#pragma unroll
        for (int ks = 0; ks < 2; ks++) {
            b0[ks] = *(const s16x8*)&Wt[t & 1][ks * 4 + kq][r16][0];
            b1[ks] = *(const s16x8*)&Wt[t & 1][ks * 4 + kq][16 + r16][0];
        }
        if (t < 7) {
#pragma unroll
            for (int ks = 0; ks < 2; ks++)
                af[(t + 1) & 1][ks] = *(const s16x8*)(ap + (t + 1) * 64 + ks * 32);
        }
        if (t < 6) {
#pragma unroll
            for (int j = 0; j < 8; j++) wr[t & 1][j] = wsrc[(size_t)((t + 2) * 64 + j) * 1024];
        }
#pragma unroll
        for (int ks = 0; ks < 2; ks++) {
            acc[0] = __builtin_amdgcn_mfma_f32_16x16x32_bf16(af[t & 1][ks], b0[ks], acc[0], 0, 0, 0);
            acc[1] = __builtin_amdgcn_mfma_f32_16x16x32_bf16(af[t & 1][ks], b1[ks], acc[1], 0, 0, 0);
        }
        if (t < 7) {
            s16x8 p;
#pragma unroll
            for (int j = 0; j < 8; j++) p[j] = (short)f2bf(wr[(t + 1) & 1][j]);
            *(s16x8*)&Wt[(t + 1) & 1][skb][sn][0] = p;
        }
        __syncthreads();
    }

#pragma unroll
    for (int r = 0; r < 4; r++) {
        int rr = tl * 64 + w * 16 + kq * 4 + r;
        if (rr < n) {
            int t2 = list[base + rr];
            float sc = rwt[t2];
            float* op = out + (size_t)(t2 >> 1) * H;
#pragma unroll
            for (int nf = 0; nf < 2; nf++) {
                int col = nb * 32 + nf * 16 + r16;
                float v = acc[nf][r] + (z == 0 ? b_down[(size_t)e * 1024 + col] : 0.0f);
                atomicAdd(op + col, sc * v);
            }
        }
    }
}

extern "C" void kernel_launch(void* const* d_in, const int* in_sizes, int n_in,
                              void* d_out, int out_size, void* d_ws, size_t ws_size,
                              hipStream_t stream) {
    const float* hidden          = (const float*)d_in[0];
    const float* kv_cache        = (const float*)d_in[1];
    const int*   kv_page_indices = (const int*)d_in[3];
    const float* sinks           = (const float*)d_in[4];
    const float* w_qkv           = (const float*)d_in[5];
    const float* b_qkv           = (const float*)d_in[6];
    const float* w_o             = (const float*)d_in[7];
    const float* b_o             = (const float*)d_in[8];
    const float* ln1_w           = (const float*)d_in[9];
    const float* ln2_w           = (const float*)d_in[10];
    const float* w_router        = (const float*)d_in[11];
    const float* b_router        = (const float*)d_in[12];
    const float* w_gate_up       = (const float*)d_in[13];
    const float* b_gate_up       = (const float*)d_in[14];
    const float* w_down          = (const float*)d_in[15];
    const float* b_down          = (const float*)d_in[16];
    float* out = (float*)d_out;

    // ---- workspace layout ----
    char* base = (char*)d_ws;
    float* qkv   = (float*)base;                       base += (size_t)T_ * QKV_N * 4;
    float* hbuf  = (float*)base;                       base += (size_t)T_ * H * 4;
    unsigned short* x_bf    = (unsigned short*)base;   base += (size_t)T_ * H * 2;
    unsigned short* x2_bf   = (unsigned short*)base;   base += (size_t)T_ * H * 2;
    unsigned short* attn_bf = (unsigned short*)base;   base += (size_t)T_ * NQ * HD * 2;
    unsigned short* act_bf  = (unsigned short*)base;   base += (size_t)(MAXROWS + 128) * FFN * 2;
    float* rwt  = (float*)base;                        base += 2 * T_ * 4;
    int*   ridx = (int*)base;                          base += 2 * T_ * 4;
    int*   cnt  = (int*)base;                          base += E_ * 4;
    int*   poff = (int*)base;                          base += E_ * 4;
    int*   list = (int*)base;                          base += MAXROWS * 4;

    rmsnorm_kernel<<<T_, 256, 0, stream>>>(hidden, ln1_w, x_bf, cnt);
    gemm_dense_t<<<dim3(QKV_N / 32, T_ / 64), 256, 0, stream>>>(
        x_bf, w_qkv, b_qkv, nullptr, qkv, nullptr, QKV_N);
    attn_group_kernel<<<B_ * Q_ * NKV, 256, 0, stream>>>(qkv, kv_cache, kv_page_indices, sinks, attn_bf);
    gemm_dense_t<<<dim3(H / 32, T_ / 64), 256, 0, stream>>>(
        attn_bf, w_o, b_o, hidden, hbuf, out, H);
    rms_router_kernel<<<T_, 256, 0, stream>>>(hbuf, ln2_w, w_router, b_router,
                                              x2_bf, ridx, rwt, cnt);
    plumb_kernel<<<1, 256, 0, stream>>>(cnt, ridx, poff, list);
    moe_gateup_t<<<dim3(FFN * 2 / 32, E_ * 16), 256, 0, stream>>>(
        x2_bf, list, cnt, poff, w_gate_up, b_gate_up, act_bf);
    moe_down_t<<<dim3(H / 32, E_ * 16, 2), 256, 0, stream>>>(
        act_bf, list, cnt, poff, rwt, w_down, b_down, out);
}

// Round 5
// 274.687 us; speedup vs baseline: 1.2209x; 1.0569x over previous
//
#include <hip/hip_runtime.h>

// ---- static config (mirrors reference) ----
constexpr int H    = 1024;
constexpr int HD   = 64;
constexpr int NQ   = 16;
constexpr int NKV  = 4;
constexpr int E_   = 8;
constexpr int FFN  = 1024;
constexpr int B_   = 4;
constexpr int Q_   = 128;
constexpr int P_   = 8;
constexpr int PS   = 128;
constexpr int S_   = P_ * PS;                 // 1024
constexpr int T_   = B_ * Q_;                 // 512
constexpr int QKV_N = HD * (NQ + 2 * NKV);    // 1536
constexpr float EPS   = 1e-5f;
constexpr float ALPHA = 1.702f;
constexpr float LIMIT = 7.0f;
constexpr float SCALE = 0.125f;               // HD^-0.5

constexpr int MAXROWS = 1536;                 // 1024 assignments + per-expert pad to 64
constexpr int MAXTILES = 24;                  // MAXROWS / 64

typedef __attribute__((ext_vector_type(4))) float f32x4;
typedef __attribute__((ext_vector_type(8))) short s16x8;

__device__ __forceinline__ unsigned short f2bf(float f) {
    unsigned u = __float_as_uint(f);
    u += 0x7FFFu + ((u >> 16) & 1u);
    return (unsigned short)(u >> 16);
}

// ---------------- RMSNorm -> bf16 out (also zeroes cnt once) ----------------
__global__ __launch_bounds__(256) void rmsnorm_kernel(const float* __restrict__ in,
                                                      const float* __restrict__ w,
                                                      unsigned short* __restrict__ outb,
                                                      int* __restrict__ cnt) {
    int t   = blockIdx.x;
    int tid = threadIdx.x;
    if (t == 0 && tid < E_) cnt[tid] = 0;
    float4 v = ((const float4*)(in + (size_t)t * H))[tid];
    float ss = v.x * v.x + v.y * v.y + v.z * v.z + v.w * v.w;
#pragma unroll
    for (int off = 32; off; off >>= 1) ss += __shfl_down(ss, off);
    __shared__ float partial[4];
    __shared__ float s_inv;
    if ((tid & 63) == 0) partial[tid >> 6] = ss;
    __syncthreads();
    if (tid == 0)
        s_inv = rsqrtf((partial[0] + partial[1] + partial[2] + partial[3]) * (1.0f / H) + EPS);
    __syncthreads();
    float inv = s_inv;
    float4 wv = ((const float4*)w)[tid];
    ushort4 ob;
    ob.x = f2bf(v.x * wv.x * inv); ob.y = f2bf(v.y * wv.y * inv);
    ob.z = f2bf(v.z * wv.z * inv); ob.w = f2bf(v.w * wv.w * inv);
    ((ushort4*)(outb + (size_t)t * H))[tid] = ob;
}

// ---------------- tiled dense GEMM: A bf16 [M][1024] x W f32 [1024][N] ----------------
// BM=64 (4 waves x 16 rows), BN=32, BK=64; pipelined: W 2-deep, A 1-deep, 1 barrier/iter.
__global__ __launch_bounds__(256, 4) void gemm_dense_t(const unsigned short* __restrict__ Abf,
                                                       const float* __restrict__ W,
                                                       const float* __restrict__ bias,
                                                       const float* __restrict__ resid,
                                                       float* __restrict__ C,
                                                       float* __restrict__ Cdup, int N) {
    int nb = blockIdx.x, mb = blockIdx.y * 64;
    int tid = threadIdx.x;
    int w = tid >> 6, lane = tid & 63;
    int r16 = lane & 15, kq = lane >> 4;
    int skb = tid >> 5, sn = tid & 31;

    __shared__ unsigned short Wt[2][8][32][8];

    size_t sN = (size_t)N;
    const float* wsrc = W + (size_t)(skb * 8) * sN + nb * 32 + sn;
    const unsigned short* ap = Abf + (size_t)(mb + w * 16 + r16) * 1024 + kq * 8;

    float wr[2][8];
    s16x8 af[2][2];
    f32x4 acc[2] = {};

#pragma unroll
    for (int j = 0; j < 8; j++) wr[0][j] = wsrc[(size_t)j * sN];
    {
        s16x8 p;
#pragma unroll
        for (int j = 0; j < 8; j++) p[j] = (short)f2bf(wr[0][j]);
        *(s16x8*)&Wt[0][skb][sn][0] = p;
    }
#pragma unroll
    for (int j = 0; j < 8; j++) wr[1][j] = wsrc[(size_t)(64 + j) * sN];
#pragma unroll
    for (int ks = 0; ks < 2; ks++) af[0][ks] = *(const s16x8*)(ap + ks * 32);
    __syncthreads();

#pragma unroll
    for (int t = 0; t < 16; t++) {
        s16x8 b0[2], b1[2];
#pragma unroll
        for (int ks = 0; ks < 2; ks++) {
            b0[ks] = *(const s16x8*)&Wt[t & 1][ks * 4 + kq][r16][0];
            b1[ks] = *(const s16x8*)&Wt[t & 1][ks * 4 + kq][16 + r16][0];
        }
        if (t < 15) {
#pragma unroll
            for (int ks = 0; ks < 2; ks++)
                af[(t + 1) & 1][ks] = *(const s16x8*)(ap + (t + 1) * 64 + ks * 32);
        }
        if (t < 14) {
#pragma unroll
            for (int j = 0; j < 8; j++) wr[t & 1][j] = wsrc[(size_t)((t + 2) * 64 + j) * sN];
        }
#pragma unroll
        for (int ks = 0; ks < 2; ks++) {
            acc[0] = __builtin_amdgcn_mfma_f32_16x16x32_bf16(af[t & 1][ks], b0[ks], acc[0], 0, 0, 0);
            acc[1] = __builtin_amdgcn_mfma_f32_16x16x32_bf16(af[t & 1][ks], b1[ks], acc[1], 0, 0, 0);
        }
        if (t < 15) {
            s16x8 p;
#pragma unroll
            for (int j = 0; j < 8; j++) p[j] = (short)f2bf(wr[(t + 1) & 1][j]);
            *(s16x8*)&Wt[(t + 1) & 1][skb][sn][0] = p;
        }
        __syncthreads();
    }

    int row0 = mb + w * 16 + kq * 4;
#pragma unroll
    for (int nf = 0; nf < 2; nf++) {
        int col = nb * 32 + nf * 16 + r16;
        float bcol = bias[col];
#pragma unroll
        for (int r = 0; r < 4; r++) {
            int row = row0 + r;
            float v = acc[nf][r] + bcol;
            if (resid) v += resid[(size_t)row * sN + col];
            C[(size_t)row * sN + col] = v;
            if (Cdup) Cdup[(size_t)row * sN + col] = v;
        }
    }
}

// ---------------- Attention: one block per (b, q, kvh); 4 heads/block; bf16 out ----------------
__global__ __launch_bounds__(256) void attn_group_kernel(const float* __restrict__ qkv,
                                                         const float* __restrict__ kv_cache,
                                                         const int* __restrict__ page_idx,
                                                         const float* __restrict__ sinks,
                                                         unsigned short* __restrict__ attn_bf) {
    int blk = blockIdx.x;
    int kvh = blk & 3;
    int q   = (blk >> 2) & 127;
    int b   = blk >> 9;
    int t   = b * Q_ + q;
    int tid = threadIdx.x;
    int s_lo = S_ - Q_ - 127 + q;

    __shared__ __align__(16) float Vs[128][64];
    __shared__ __align__(16) float qs4[4][64];
    __shared__ float pv[4][128];
    __shared__ float sD[4];

#pragma unroll
    for (int r = 0; r < 8; r++) {
        int l = r * 256 + tid;
        int key = l >> 4, c = l & 15;
        int s = s_lo + key;
        const float* vp;
        if (s < S_ - Q_) {
            int page = page_idx[b * P_ + (s >> 7)];
            vp = kv_cache + (size_t)page * 65536 + 32768 + (size_t)(s & 127) * (NKV * HD) + kvh * HD;
        } else {
            vp = qkv + (size_t)(b * Q_ + (s - (S_ - Q_))) * QKV_N + (NQ + NKV) * HD + kvh * HD;
        }
        ((float4*)Vs[key])[c] = *(const float4*)(vp + c * 4);
    }
    {
        int hh = tid >> 6, d2 = tid & 63;
        qs4[hh][d2] = qkv[(size_t)t * QKV_N + (kvh * 4 + hh) * HD + d2];
    }
    __syncthreads();

    {
        int key = tid & 127, hp = tid >> 7;
        int s = s_lo + key;
        const float* kp;
        if (s < S_ - Q_) {
            int page = page_idx[b * P_ + (s >> 7)];
            kp = kv_cache + (size_t)page * 65536 + (size_t)(s & 127) * (NKV * HD) + kvh * HD;
        } else {
            kp = qkv + (size_t)(b * Q_ + (s - (S_ - Q_))) * QKV_N + NQ * HD + kvh * HD;
        }
        const float4* kp4 = (const float4*)kp;
        const float4* q0p = (const float4*)qs4[hp * 2];
        const float4* q1p = (const float4*)qs4[hp * 2 + 1];
        float sc0 = 0.f, sc1 = 0.f;
#pragma unroll
        for (int d4 = 0; d4 < 16; d4++) {
            float4 kk = kp4[d4];
            float4 q0 = q0p[d4], q1 = q1p[d4];
            sc0 += q0.x * kk.x + q0.y * kk.y + q0.z * kk.z + q0.w * kk.w;
            sc1 += q1.x * kk.x + q1.y * kk.y + q1.z * kk.z + q1.w * kk.w;
        }
        pv[hp * 2][key]     = sc0 * SCALE;
        pv[hp * 2 + 1][key] = sc1 * SCALE;
    }
    __syncthreads();

    {
        int wv = tid >> 6, lane = tid & 63;
        float a0 = pv[wv][lane], a1 = pv[wv][lane + 64];
        float m = fmaxf(a0, a1);
#pragma unroll
        for (int off = 32; off; off >>= 1) m = fmaxf(m, __shfl_xor(m, off));
        float p0 = __expf(a0 - m), p1 = __expf(a1 - m);
        float l = p0 + p1;
#pragma unroll
        for (int off = 32; off; off >>= 1) l += __shfl_xor(l, off);
        pv[wv][lane] = p0;
        pv[wv][lane + 64] = p1;
        if (lane == 0) sD[wv] = l + __expf(sinks[kvh * 4 + wv] - m);
    }
    __syncthreads();

    {
        int hh = tid >> 6, d2 = tid & 63;
        float a0 = 0.f, a1 = 0.f, a2 = 0.f, a3 = 0.f;
#pragma unroll 4
        for (int i = 0; i < 128; i += 4) {
            a0 += pv[hh][i]     * Vs[i][d2];
            a1 += pv[hh][i + 1] * Vs[i + 1][d2];
            a2 += pv[hh][i + 2] * Vs[i + 2][d2];
            a3 += pv[hh][i + 3] * Vs[i + 3][d2];
        }
        float acc = ((a0 + a1) + (a2 + a3)) / sD[hh];
        attn_bf[(size_t)t * (NQ * HD) + (kvh * 4 + hh) * HD + d2] = f2bf(acc);
    }
}

// ---------------- fused RMSNorm2 + router ----------------
__global__ __launch_bounds__(256) void rms_router_kernel(const float* __restrict__ hbuf,
                                                         const float* __restrict__ ln2w,
                                                         const float* __restrict__ w_router,
                                                         const float* __restrict__ b_router,
                                                         unsigned short* __restrict__ x2bf,
                                                         int* __restrict__ ridx,
                                                         float* __restrict__ rwt,
                                                         int* __restrict__ cnt) {
    int t = blockIdx.x;
    int tid = threadIdx.x;
    float4 v = ((const float4*)(hbuf + (size_t)t * H))[tid];
    float ss = v.x * v.x + v.y * v.y + v.z * v.z + v.w * v.w;
#pragma unroll
    for (int off = 32; off; off >>= 1) ss += __shfl_down(ss, off);
    __shared__ float partial[4];
    __shared__ float s_inv;
    if ((tid & 63) == 0) partial[tid >> 6] = ss;
    __syncthreads();
    if (tid == 0)
        s_inv = rsqrtf((partial[0] + partial[1] + partial[2] + partial[3]) * (1.0f / H) + EPS);
    __syncthreads();
    float inv = s_inv;
    float4 wv = ((const float4*)ln2w)[tid];
    float4 o;
    o.x = v.x * wv.x * inv; o.y = v.y * wv.y * inv;
    o.z = v.z * wv.z * inv; o.w = v.w * wv.w * inv;
    ushort4 ob;
    ob.x = f2bf(o.x); ob.y = f2bf(o.y); ob.z = f2bf(o.z); ob.w = f2bf(o.w);
    ((ushort4*)(x2bf + (size_t)t * H))[tid] = ob;

    const float4* wr = (const float4*)(w_router + (size_t)tid * 4 * E_);
    float p[E_];
    {
        float4 r0a = wr[0], r0b = wr[1];
        float4 r1a = wr[2], r1b = wr[3];
        float4 r2a = wr[4], r2b = wr[5];
        float4 r3a = wr[6], r3b = wr[7];
        p[0] = o.x * r0a.x + o.y * r1a.x + o.z * r2a.x + o.w * r3a.x;
        p[1] = o.x * r0a.y + o.y * r1a.y + o.z * r2a.y + o.w * r3a.y;
        p[2] = o.x * r0a.z + o.y * r1a.z + o.z * r2a.z + o.w * r3a.z;
        p[3] = o.x * r0a.w + o.y * r1a.w + o.z * r2a.w + o.w * r3a.w;
        p[4] = o.x * r0b.x + o.y * r1b.x + o.z * r2b.x + o.w * r3b.x;
        p[5] = o.x * r0b.y + o.y * r1b.y + o.z * r2b.y + o.w * r3b.y;
        p[6] = o.x * r0b.z + o.y * r1b.z + o.z * r2b.z + o.w * r3b.z;
        p[7] = o.x * r0b.w + o.y * r1b.w + o.z * r2b.w + o.w * r3b.w;
    }
    __shared__ float wsum[4][E_];
    int wv2 = tid >> 6, lane = tid & 63;
#pragma unroll
    for (int e = 0; e < E_; e++) {
        float r = p[e];
#pragma unroll
        for (int off = 32; off; off >>= 1) r += __shfl_xor(r, off);
        if (lane == 0) wsum[wv2][e] = r;
    }
    __syncthreads();
    __shared__ float logits[E_];
    if (tid < E_)
        logits[tid] = wsum[0][tid] + wsum[1][tid] + wsum[2][tid] + wsum[3][tid] + b_router[tid];
    __syncthreads();
    if (tid == 0) {
        int i0 = 0; float v0 = logits[0];
        for (int ee = 1; ee < E_; ee++)
            if (logits[ee] > v0) { v0 = logits[ee]; i0 = ee; }
        int i1 = -1; float v1 = -3.4e38f;
        for (int ee = 0; ee < E_; ee++)
            if (ee != i0 && logits[ee] > v1) { v1 = logits[ee]; i1 = ee; }
        float w0 = 1.0f / (1.0f + __expf(v1 - v0));
        ridx[t * 2] = i0; ridx[t * 2 + 1] = i1;
        rwt[t * 2] = w0;  rwt[t * 2 + 1] = 1.0f - w0;
        atomicAdd(&cnt[i0], 1);
        atomicAdd(&cnt[i1], 1);
    }
}

// ---------------- plumb: offsets + flat tile map + scatter ----------------
// tmap[0] = ntiles; tmap[1+i] = (e<<5)|tl  -- flat list so working blocks are
// CONTIGUOUS in linear block-id space (spread evenly across CUs/XCDs).
__global__ __launch_bounds__(256) void plumb_kernel(const int* __restrict__ cnt,
                                                    const int* __restrict__ ridx,
                                                    int* __restrict__ poff,
                                                    int* __restrict__ list,
                                                    int* __restrict__ tmap) {
    __shared__ int lpos[E_], lpoff[E_];
    int tid = threadIdx.x;
    if (tid == 0) {
        int run = 0, it = 0;
        for (int e = 0; e < E_; e++) {
            lpoff[e] = run; poff[e] = run;
            int pc = (cnt[e] + 63) & ~63;
            for (int tl = 0; tl < (pc >> 6); tl++) tmap[1 + it++] = (e << 5) | tl;
            run += pc;
        }
        tmap[0] = it;
    }
    if (tid < E_) lpos[tid] = 0;
    __syncthreads();
    for (int i = tid; i < 2 * T_; i += 256) {
        int e = ridx[i];
        int pp = atomicAdd(&lpos[e], 1);
        list[lpoff[e] + pp] = i;
    }
}

// ---------------- tiled grouped gate_up GEMM + swiglu ----------------
// BM=64 (4 waves x 16 rows), BN=32 interleaved gu-cols (=16 f cols), BK=64, pipelined.
// grid: x = 2048/32 = 64, y = flat tile idx (MAXTILES), early exit on y>=ntiles.
__global__ __launch_bounds__(256, 4) void moe_gateup_t(const unsigned short* __restrict__ x2bf,
                                                       const int* __restrict__ list,
                                                       const int* __restrict__ cnt,
                                                       const int* __restrict__ poff,
                                                       const int* __restrict__ tmap,
                                                       const float* __restrict__ wgu,
                                                       const float* __restrict__ bgu,
                                                       unsigned short* __restrict__ act_bf) {
    if ((int)blockIdx.y >= tmap[0]) return;
    int v0m = tmap[1 + blockIdx.y];
    int e = v0m >> 5, tl = v0m & 31;
    int n = cnt[e];
    int base = poff[e];
    int nb = blockIdx.x;
    int tid = threadIdx.x;
    int w = tid >> 6, lane = tid & 63;
    int r16 = lane & 15, kq = lane >> 4;
    int skb = tid >> 5, sn = tid & 31;

    __shared__ unsigned short Wt[2][8][32][8];

    const float* wsrc = wgu + (size_t)e * (1024 * 2048) + (size_t)(skb * 8) * 2048 + nb * 32 + sn;
    int rr0 = tl * 64 + w * 16 + r16;
    int t2a = (rr0 < n) ? list[base + rr0] : list[base];
    const unsigned short* ap = x2bf + (size_t)(t2a >> 1) * 1024 + kq * 8;

    float wr[2][8];
    s16x8 af[2][2];
    f32x4 acc[2] = {};

#pragma unroll
    for (int j = 0; j < 8; j++) wr[0][j] = wsrc[(size_t)j * 2048];
    {
        s16x8 p;
#pragma unroll
        for (int j = 0; j < 8; j++) p[j] = (short)f2bf(wr[0][j]);
        *(s16x8*)&Wt[0][skb][sn][0] = p;
    }
#pragma unroll
    for (int j = 0; j < 8; j++) wr[1][j] = wsrc[(size_t)(64 + j) * 2048];
#pragma unroll
    for (int ks = 0; ks < 2; ks++) af[0][ks] = *(const s16x8*)(ap + ks * 32);
    __syncthreads();

#pragma unroll
    for (int t = 0; t < 16; t++) {
        s16x8 b0[2], b1[2];
#pragma unroll
        for (int ks = 0; ks < 2; ks++) {
            b0[ks] = *(const s16x8*)&Wt[t & 1][ks * 4 + kq][r16][0];
            b1[ks] = *(const s16x8*)&Wt[t & 1][ks * 4 + kq][16 + r16][0];
        }
        if (t < 15) {
#pragma unroll
            for (int ks = 0; ks < 2; ks++)
                af[(t + 1) & 1][ks] = *(const s16x8*)(ap + (t + 1) * 64 + ks * 32);
        }
        if (t < 14) {
#pragma unroll
            for (int j = 0; j < 8; j++) wr[t & 1][j] = wsrc[(size_t)((t + 2) * 64 + j) * 2048];
        }
#pragma unroll
        for (int ks = 0; ks < 2; ks++) {
            acc[0] = __builtin_amdgcn_mfma_f32_16x16x32_bf16(af[t & 1][ks], b0[ks], acc[0], 0, 0, 0);
            acc[1] = __builtin_amdgcn_mfma_f32_16x16x32_bf16(af[t & 1][ks], b1[ks], acc[1], 0, 0, 0);
        }
        if (t < 15) {
            s16x8 p;
#pragma unroll
            for (int j = 0; j < 8; j++) p[j] = (short)f2bf(wr[(t + 1) & 1][j]);
            *(s16x8*)&Wt[(t + 1) & 1][skb][sn][0] = p;
        }
        __syncthreads();
    }

    // epilogue: gate on even gu-cols, up on odd; pair via shfl_xor lane^1
    int parity = r16 & 1;
#pragma unroll
    for (int nf = 0; nf < 2; nf++) {
        int gucol = nb * 32 + nf * 16 + r16;
        float bb = bgu[(size_t)e * 2048 + gucol];
#pragma unroll
        for (int r = 0; r < 4; r++) {
            float v = acc[nf][r] + bb;
            float o = __shfl_xor(v, 1);
            if (!parity) {
                float g = fminf(v, LIMIT);
                float u = fminf(fmaxf(o, -LIMIT), LIMIT);
                float glu = g / (1.0f + __expf(-ALPHA * g));
                int rr = tl * 64 + w * 16 + kq * 4 + r;
                if (rr < n)
                    act_bf[(size_t)(base + rr) * FFN + (gucol >> 1)] = f2bf((u + 1.0f) * glu);
            }
        }
    }
}

// ---------------- tiled grouped down GEMM, split-K z=2, atomicAdd epilogue ----------------
// BM=64, BN=32, BK=64, pipelined. grid: x = 1024/32 = 32, y = flat tile idx, z = 2 (K halves)
__global__ __launch_bounds__(256, 4) void moe_down_t(const unsigned short* __restrict__ act_bf,
                                                     const int* __restrict__ list,
                                                     const int* __restrict__ cnt,
                                                     const int* __restrict__ poff,
                                                     const int* __restrict__ tmap,
                                                     const float* __restrict__ rwt,
                                                     const float* __restrict__ wdn,
                                                     const float* __restrict__ b_down,
                                                     float* __restrict__ out) {
    if ((int)blockIdx.y >= tmap[0]) return;
    int v0m = tmap[1 + blockIdx.y];
    int e = v0m >> 5, tl = v0m & 31;
    int n = cnt[e];
    int base = poff[e];
    int nb = blockIdx.x;
    int z  = blockIdx.z;
    int tid = threadIdx.x;
    int w = tid >> 6, lane = tid & 63;
    int r16 = lane & 15, kq = lane >> 4;
    int skb = tid >> 5, sn = tid & 31;

    __shared__ unsigned short Wt[2][8][32][8];

    const float* wsrc = wdn + (size_t)e * (1024 * 1024) + (size_t)(z * 512 + skb * 8) * 1024 + nb * 32 + sn;
    const unsigned short* ap = act_bf + (size_t)(base + tl * 64 + w * 16 + r16) * 1024 + z * 512 + kq * 8;

    float wr[2][8];
    s16x8 af[2][2];
    f32x4 acc[2] = {};

#pragma unroll
    for (int j = 0; j < 8; j++) wr[0][j] = wsrc[(size_t)j * 1024];
    {
        s16x8 p;
#pragma unroll
        for (int j = 0; j < 8; j++) p[j] = (short)f2bf(wr[0][j]);
        *(s16x8*)&Wt[0][skb][sn][0] = p;
    }
#pragma unroll
    for (int j = 0; j < 8; j++) wr[1][j] = wsrc[(size_t)(64 + j) * 1024];
#pragma unroll
    for (int ks = 0; ks < 2; ks++) af[0][ks] = *(const s16x8*)(ap + ks * 32);
    __syncthreads();

#pragma unroll
    for (int t = 0; t < 8; t++) {
        s16x8 b0[2], b1[2];
#pragma unroll
        for (int ks = 0; ks < 2; ks++) {
            b0[ks] = *(const s16x8*)&Wt[t & 1][ks * 4 + kq][r16][0];
            b1[ks] = *(const s16x8*)&Wt[t & 1][ks * 4 + kq][16 + r16][0];
        }
        if (t < 7) {
#pragma unroll
            for (int ks = 0; ks < 2; ks++)
                af[(t + 1) & 1][ks] = *(const s16x8*)(ap + (t + 1) * 64 + ks * 32);
        }
        if (t < 6) {
#pragma unroll
            for (int j = 0; j < 8; j++) wr[t & 1][j] = wsrc[(size_t)((t + 2) * 64 + j) * 1024];
        }
#pragma unroll
        for (int ks = 0; ks < 2; ks++) {
            acc[0] = __builtin_amdgcn_mfma_f32_16x16x32_bf16(af[t & 1][ks], b0[ks], acc[0], 0, 0, 0);
            acc[1] = __builtin_amdgcn_mfma_f32_16x16x32_bf16(af[t & 1][ks], b1[ks], acc[1], 0, 0, 0);
        }
        if (t < 7) {
            s16x8 p;
#pragma unroll
            for (int j = 0; j < 8; j++) p[j] = (short)f2bf(wr[(t + 1) & 1][j]);
            *(s16x8*)&Wt[(t + 1) & 1][skb][sn][0] = p;
        }
        __syncthreads();
    }

#pragma unroll
    for (int r = 0; r < 4; r++) {
        int rr = tl * 64 + w * 16 + kq * 4 + r;
        if (rr < n) {
            int t2 = list[base + rr];
            float sc = rwt[t2];
            float* op = out + (size_t)(t2 >> 1) * H;
#pragma unroll
            for (int nf = 0; nf < 2; nf++) {
                int col = nb * 32 + nf * 16 + r16;
                float v = acc[nf][r] + (z == 0 ? b_down[(size_t)e * 1024 + col] : 0.0f);
                atomicAdd(op + col, sc * v);
            }
        }
    }
}

extern "C" void kernel_launch(void* const* d_in, const int* in_sizes, int n_in,
                              void* d_out, int out_size, void* d_ws, size_t ws_size,
                              hipStream_t stream) {
    const float* hidden          = (const float*)d_in[0];
    const float* kv_cache        = (const float*)d_in[1];
    const int*   kv_page_indices = (const int*)d_in[3];
    const float* sinks           = (const float*)d_in[4];
    const float* w_qkv           = (const float*)d_in[5];
    const float* b_qkv           = (const float*)d_in[6];
    const float* w_o             = (const float*)d_in[7];
    const float* b_o             = (const float*)d_in[8];
    const float* ln1_w           = (const float*)d_in[9];
    const float* ln2_w           = (const float*)d_in[10];
    const float* w_router        = (const float*)d_in[11];
    const float* b_router        = (const float*)d_in[12];
    const float* w_gate_up       = (const float*)d_in[13];
    const float* b_gate_up       = (const float*)d_in[14];
    const float* w_down          = (const float*)d_in[15];
    const float* b_down          = (const float*)d_in[16];
    float* out = (float*)d_out;

    // ---- workspace layout ----
    char* base = (char*)d_ws;
    float* qkv   = (float*)base;                       base += (size_t)T_ * QKV_N * 4;
    float* hbuf  = (float*)base;                       base += (size_t)T_ * H * 4;
    unsigned short* x_bf    = (unsigned short*)base;   base += (size_t)T_ * H * 2;
    unsigned short* x2_bf   = (unsigned short*)base;   base += (size_t)T_ * H * 2;
    unsigned short* attn_bf = (unsigned short*)base;   base += (size_t)T_ * NQ * HD * 2;
    unsigned short* act_bf  = (unsigned short*)base;   base += (size_t)(MAXROWS + 128) * FFN * 2;
    float* rwt  = (float*)base;                        base += 2 * T_ * 4;
    int*   ridx = (int*)base;                          base += 2 * T_ * 4;
    int*   cnt  = (int*)base;                          base += E_ * 4;
    int*   poff = (int*)base;                          base += E_ * 4;
    int*   list = (int*)base;                          base += MAXROWS * 4;
    int*   tmap = (int*)base;                          base += (1 + MAXTILES + 7) * 4;

    rmsnorm_kernel<<<T_, 256, 0, stream>>>(hidden, ln1_w, x_bf, cnt);
    gemm_dense_t<<<dim3(QKV_N / 32, T_ / 64), 256, 0, stream>>>(
        x_bf, w_qkv, b_qkv, nullptr, qkv, nullptr, QKV_N);
    attn_group_kernel<<<B_ * Q_ * NKV, 256, 0, stream>>>(qkv, kv_cache, kv_page_indices, sinks, attn_bf);
    gemm_dense_t<<<dim3(H / 32, T_ / 64), 256, 0, stream>>>(
        attn_bf, w_o, b_o, hidden, hbuf, out, H);
    rms_router_kernel<<<T_, 256, 0, stream>>>(hbuf, ln2_w, w_router, b_router,
                                              x2_bf, ridx, rwt, cnt);
    plumb_kernel<<<1, 256, 0, stream>>>(cnt, ridx, poff, list, tmap);
    moe_gateup_t<<<dim3(FFN * 2 / 32, MAXTILES), 256, 0, stream>>>(
        x2_bf, list, cnt, poff, tmap, w_gate_up, b_gate_up, act_bf);
    moe_down_t<<<dim3(H / 32, MAXTILES, 2), 256, 0, stream>>>(
        act_bf, list, cnt, poff, tmap, rwt, w_down, b_down, out);
}